// Round 1
// baseline (24791.695 us; speedup 1.0000x reference)
//
#include <hip/hip_runtime.h>
#include <cmath>

// Problem constants (fixed by the reference file)
#define B_ 1024
#define F_ 4096
#define V_ 20000
#define E_ 512
#define H_ 1024
#define L_ 20
#define D_ 4

// ---------------------------------------------------------------------------
// Generic fp32 NT GEMM: C[M,N] = A[M,K] @ W[N,K]^T (+ b1 + b2) (+= C if accum)
// 128x128 tile, BK=16, 256 threads, 8x8 microtile. K must be a multiple of 16
// (all K here are 512/1024/4096). M,N guarded (N=20000 has a 32-col tail).
// ---------------------------------------------------------------------------
#define BM 128
#define BN 128
#define BK 16

__global__ __launch_bounds__(256) void gemm_nt_bias(
    const float* __restrict__ A, const float* __restrict__ W,
    const float* __restrict__ b1, const float* __restrict__ b2,
    float* __restrict__ C, int M, int N, int K, int accum)
{
    __shared__ __align__(16) float As[BK][BM + 4];
    __shared__ __align__(16) float Ws[BK][BN + 4];
    const int tid = threadIdx.x;
    const int bm = blockIdx.y * BM;
    const int bn = blockIdx.x * BN;
    const int lrow = tid >> 1;        // 0..127
    const int lk   = (tid & 1) * 8;   // 0 or 8
    const int ty = tid >> 4;          // 0..15
    const int tx = tid & 15;          // 0..15

    float acc[8][8];
#pragma unroll
    for (int i = 0; i < 8; ++i)
#pragma unroll
        for (int j = 0; j < 8; ++j) acc[i][j] = 0.f;

    const int arow = bm + lrow;
    const int wrow = bn + lrow;
    const float* Ap = A + (size_t)arow * K + lk;
    const float* Wp = W + (size_t)wrow * K + lk;
    const bool aok = arow < M;
    const bool wok = wrow < N;

    for (int k0 = 0; k0 < K; k0 += BK) {
        float4 a0 = make_float4(0.f, 0.f, 0.f, 0.f), a1 = a0, w0 = a0, w1 = a0;
        if (aok) {
            a0 = *(const float4*)(Ap + k0);
            a1 = *(const float4*)(Ap + k0 + 4);
        }
        if (wok) {
            w0 = *(const float4*)(Wp + k0);
            w1 = *(const float4*)(Wp + k0 + 4);
        }
        __syncthreads();   // previous iteration's readers done before overwrite
        As[lk + 0][lrow] = a0.x; As[lk + 1][lrow] = a0.y;
        As[lk + 2][lrow] = a0.z; As[lk + 3][lrow] = a0.w;
        As[lk + 4][lrow] = a1.x; As[lk + 5][lrow] = a1.y;
        As[lk + 6][lrow] = a1.z; As[lk + 7][lrow] = a1.w;
        Ws[lk + 0][lrow] = w0.x; Ws[lk + 1][lrow] = w0.y;
        Ws[lk + 2][lrow] = w0.z; Ws[lk + 3][lrow] = w0.w;
        Ws[lk + 4][lrow] = w1.x; Ws[lk + 5][lrow] = w1.y;
        Ws[lk + 6][lrow] = w1.z; Ws[lk + 7][lrow] = w1.w;
        __syncthreads();
#pragma unroll
        for (int kk = 0; kk < BK; ++kk) {
            float a[8], b[8];
            *(float4*)&a[0] = *(const float4*)&As[kk][ty * 8];
            *(float4*)&a[4] = *(const float4*)&As[kk][ty * 8 + 4];
            *(float4*)&b[0] = *(const float4*)&Ws[kk][tx * 8];
            *(float4*)&b[4] = *(const float4*)&Ws[kk][tx * 8 + 4];
#pragma unroll
            for (int i = 0; i < 8; ++i)
#pragma unroll
                for (int j = 0; j < 8; ++j)
                    acc[i][j] = fmaf(a[i], b[j], acc[i][j]);
        }
    }

#pragma unroll
    for (int i = 0; i < 8; ++i) {
        int r = bm + ty * 8 + i;
        if (r >= M) continue;
        float* Crow = C + (size_t)r * N;
#pragma unroll
        for (int j = 0; j < 8; ++j) {
            int cidx = bn + tx * 8 + j;
            if (cidx >= N) continue;
            float v = acc[i][j];
            if (b1) v += b1[cidx];
            if (b2) v += b2[cidx];
            if (accum) v += Crow[cidx];
            Crow[cidx] = v;
        }
    }
}

// ---------------------------------------------------------------------------
// LSTM pointwise: gates [B,4H] (i,f,g,o), updates c,h in place.
// ---------------------------------------------------------------------------
__global__ __launch_bounds__(256) void lstm_pointwise(
    const float* __restrict__ gates, float* __restrict__ c, float* __restrict__ h)
{
    int i = blockIdx.x * blockDim.x + threadIdx.x;
    if (i >= B_ * H_) return;
    int b = i / H_, k = i % H_;
    const float* g = gates + (size_t)b * 4 * H_;
    float gi = g[k], gf = g[H_ + k], gg = g[2 * H_ + k], go = g[3 * H_ + k];
    float si = 1.f / (1.f + expf(-gi));
    float sf = 1.f / (1.f + expf(-gf));
    float so = 1.f / (1.f + expf(-go));
    float cn = sf * c[i] + si * tanhf(gg);
    c[i] = cn;
    h[i] = so * tanhf(cn);
}

// ---------------------------------------------------------------------------
// Per-row argmax (first-occurrence, numpy semantics) + online logsumexp.
// lp = max_logit - logsumexp (log-prob of the greedy token).
// ---------------------------------------------------------------------------
__global__ __launch_bounds__(256) void row_argmax_lse(
    const float* __restrict__ logits, int* __restrict__ tok,
    float* __restrict__ lp, int need_lp)
{
    int b = blockIdx.x;
    const float* row = logits + (size_t)b * V_;
    int tid = threadIdx.x;
    float m = -INFINITY; int mi = 0;
    float lm = -INFINITY, ls = 0.f;
    for (int j = tid; j < V_; j += 256) {
        float v = row[j];
        if (v > m) { m = v; mi = j; }
        if (need_lp) {
            if (v > lm) { ls = ls * expf(lm - v) + 1.f; lm = v; }
            else ls += expf(v - lm);
        }
    }
    __shared__ float sm[256]; __shared__ int si[256];
    __shared__ float slm[256], sls[256];
    sm[tid] = m; si[tid] = mi; slm[tid] = lm; sls[tid] = ls;
    __syncthreads();
    for (int s = 128; s > 0; s >>= 1) {
        if (tid < s) {
            float vm = sm[tid + s]; int vi = si[tid + s];
            if (vm > sm[tid] || (vm == sm[tid] && vi < si[tid])) {
                sm[tid] = vm; si[tid] = vi;
            }
            if (need_lp) {
                float am = slm[tid], as = sls[tid];
                float bm2 = slm[tid + s], bs = sls[tid + s];
                if (am >= bm2) {
                    sls[tid] = as + bs * expf(bm2 - am);
                } else {
                    sls[tid] = bs + as * expf(am - bm2);
                    slm[tid] = bm2;
                }
            }
        }
        __syncthreads();
    }
    if (tid == 0) {
        tok[b] = si[0];
        if (need_lp) lp[b] = sm[0] - (slm[0] + logf(sls[0]));
    }
}

// ---------------------------------------------------------------------------
// Embedding gathers
// ---------------------------------------------------------------------------
__global__ __launch_bounds__(128) void gather_emb(
    const float* __restrict__ emb, const int* __restrict__ tok,
    float* __restrict__ out)
{
    int b = blockIdx.x;
    int t = tok[b];
    const float4* src = (const float4*)(emb + (size_t)t * E_);
    float4* dst = (float4*)(out + (size_t)b * E_);
    for (int e = threadIdx.x; e < E_ / 4; e += blockDim.x) dst[e] = src[e];
}

__global__ __launch_bounds__(128) void broadcast_emb(
    const float* __restrict__ emb, const int* __restrict__ sidx,
    float* __restrict__ out)
{
    int b = blockIdx.x;
    int t = sidx[0];
    const float4* src = (const float4*)(emb + (size_t)t * E_);
    float4* dst = (float4*)(out + (size_t)b * E_);
    for (int e = threadIdx.x; e < E_ / 4; e += blockDim.x) dst[e] = src[e];
}

__global__ __launch_bounds__(256) void zero_f32(float* __restrict__ p, int n)
{
    int i = blockIdx.x * blockDim.x + threadIdx.x;
    if (i < n) p[i] = 0.f;
}

// ---------------------------------------------------------------------------
// Loss rows: sc = [5, B, B] (ts then 4 distractor score mats), lp [B].
// loss_part[i] = sum_j -hinge[i,j]*lp[j];  acc_flag[i] = (tp >= max_d dp_d)
// ---------------------------------------------------------------------------
__global__ __launch_bounds__(256) void loss_rows(
    const float* __restrict__ sc, const float* __restrict__ lp,
    float* __restrict__ loss_part, float* __restrict__ acc_flag)
{
    int i = blockIdx.x; int tid = threadIdx.x;
    const float* tsrow = sc + (size_t)i * B_;
    float lsum = 0.f, tps = 0.f;
    float dps[4] = {0.f, 0.f, 0.f, 0.f};
    for (int j = tid; j < B_; j += 256) {
        float tsv = tsrow[j];
        float hv = 0.f;
#pragma unroll
        for (int d = 0; d < 4; ++d) {
            float dv = sc[((size_t)(1 + d) * B_ + i) * B_ + j];
            float t = 1.f - tsv + dv;
            hv += (t > 0.f) ? t : 0.f;
            dps[d] += expf(dv);
        }
        lsum += hv * lp[j];
        tps += expf(tsv);
    }
    __shared__ float red[6][256];
    red[0][tid] = lsum; red[1][tid] = tps;
    red[2][tid] = dps[0]; red[3][tid] = dps[1];
    red[4][tid] = dps[2]; red[5][tid] = dps[3];
    __syncthreads();
    for (int s = 128; s > 0; s >>= 1) {
        if (tid < s) {
#pragma unroll
            for (int q = 0; q < 6; ++q) red[q][tid] += red[q][tid + s];
        }
        __syncthreads();
    }
    if (tid == 0) {
        loss_part[i] = -red[0][0];
        float tp = red[1][0];
        float mx = fmaxf(fmaxf(red[2][0], red[3][0]), fmaxf(red[4][0], red[5][0]));
        acc_flag[i] = (tp >= mx) ? 1.f : 0.f;
    }
}

__global__ __launch_bounds__(256) void finalize_k(
    const float* __restrict__ loss_part, const float* __restrict__ acc_flag,
    float* __restrict__ out)
{
    int tid = threadIdx.x;
    float ls = 0.f, ac = 0.f;
    for (int i = tid; i < B_; i += 256) { ls += loss_part[i]; ac += acc_flag[i]; }
    __shared__ float s1[256], s2[256];
    s1[tid] = ls; s2[tid] = ac;
    __syncthreads();
    for (int s = 128; s > 0; s >>= 1) {
        if (tid < s) { s1[tid] += s1[tid + s]; s2[tid] += s2[tid + s]; }
        __syncthreads();
    }
    if (tid == 0) {
        out[0] = s1[0] / ((float)B_ * (float)B_);
        out[1] = s2[0] / (float)B_;
    }
}

// ---------------------------------------------------------------------------
// Host launcher
// ---------------------------------------------------------------------------
extern "C" void kernel_launch(void* const* d_in, const int* in_sizes, int n_in,
                              void* d_out, int out_size, void* d_ws, size_t ws_size,
                              hipStream_t stream)
{
    const float* target    = (const float*)d_in[0];
    const float* distract  = (const float*)d_in[1];
    const int*   start_tok = (const int*)d_in[2];
    // d_in[3] = max_sentence_length (compile-time L_=20)
    const float* emb_s   = (const float*)d_in[4];
    const float* Wih_s   = (const float*)d_in[5];
    const float* Whh_s   = (const float*)d_in[6];
    const float* bih_s   = (const float*)d_in[7];
    const float* bhh_s   = (const float*)d_in[8];
    const float* aff_s_W = (const float*)d_in[9];
    const float* aff_s_b = (const float*)d_in[10];
    const float* probs_W = (const float*)d_in[11];
    const float* probs_b = (const float*)d_in[12];
    const float* emb_r   = (const float*)d_in[13];
    const float* Wih_r   = (const float*)d_in[14];
    const float* Whh_r   = (const float*)d_in[15];
    const float* bih_r   = (const float*)d_in[16];
    const float* bhh_r   = (const float*)d_in[17];
    const float* aff_r_W = (const float*)d_in[18];
    const float* aff_r_b = (const float*)d_in[19];

    float* ws = (float*)d_ws;
    // workspace layout (float offsets)
    const size_t OFF_HS     = 0;                 // [B,H]
    const size_t OFF_CS     = 1048576;           // [B,H]
    const size_t OFF_WE     = 2097152;           // [B,E]
    const size_t OFF_GATES  = 2621440;           // [B,4H]
    const size_t OFF_HR     = 6815744;           // [B,H]
    const size_t OFF_CR     = 7864320;           // [B,H]
    const size_t OFF_LP     = 8912896;           // [B]
    const size_t OFF_LOSSP  = 8916992;           // [B]
    const size_t OFF_ACCF   = 8921088;           // [B]
    const size_t OFF_MSG    = 8925184;           // int [L,B]
    const size_t OFF_LOGITS = 9437184;           // [B,V]   (20,480,000 floats)
    const size_t OFF_R      = 9437184;           // [B,F]   reuses logits region
    const size_t OFF_SC     = 13631488;          // [5,B,B] reuses logits region

    float* h_s    = ws + OFF_HS;
    float* c_s    = ws + OFF_CS;
    float* w_e    = ws + OFF_WE;
    float* gates  = ws + OFF_GATES;
    float* h_r    = ws + OFF_HR;
    float* c_r    = ws + OFF_CR;
    float* lp     = ws + OFF_LP;
    float* lossp  = ws + OFF_LOSSP;
    float* accf   = ws + OFF_ACCF;
    int*   msg    = (int*)(ws + OFF_MSG);
    float* logits = ws + OFF_LOGITS;
    float* r_buf  = ws + OFF_R;
    float* sc     = ws + OFF_SC;

    auto gemm = [&](const float* A, const float* W, const float* b1,
                    const float* b2, float* C, int M, int N, int K, int accum) {
        dim3 grid((N + BN - 1) / BN, (M + BM - 1) / BM);
        gemm_nt_bias<<<grid, dim3(256), 0, stream>>>(A, W, b1, b2, C, M, N, K, accum);
    };

    // ---- Sender ----
    // h0 = target @ aff_s_W.T + aff_s_b
    gemm(target, aff_s_W, aff_s_b, nullptr, h_s, B_, H_, F_, 0);
    zero_f32<<<(B_ * H_ + 255) / 256, 256, 0, stream>>>(c_s, B_ * H_);
    broadcast_emb<<<B_, 128, 0, stream>>>(emb_s, start_tok, w_e);

    for (int t = 0; t < L_; ++t) {
        gemm(w_e, Wih_s, bih_s, bhh_s, gates, B_, 4 * H_, E_, 0);
        gemm(h_s, Whh_s, nullptr, nullptr, gates, B_, 4 * H_, H_, 1);
        lstm_pointwise<<<(B_ * H_ + 255) / 256, 256, 0, stream>>>(gates, c_s, h_s);
        gemm(h_s, probs_W, probs_b, nullptr, logits, B_, V_, H_, 0);
        row_argmax_lse<<<B_, 256, 0, stream>>>(logits, msg + (size_t)t * B_, lp,
                                               (t == L_ - 1) ? 1 : 0);
        if (t < L_ - 1)
            gather_emb<<<B_, 128, 0, stream>>>(emb_s, msg + (size_t)t * B_, w_e);
    }

    // ---- Receiver ----
    zero_f32<<<(B_ * H_ + 255) / 256, 256, 0, stream>>>(h_r, B_ * H_);
    zero_f32<<<(B_ * H_ + 255) / 256, 256, 0, stream>>>(c_r, B_ * H_);
    for (int t = 0; t < L_; ++t) {
        gather_emb<<<B_, 128, 0, stream>>>(emb_r, msg + (size_t)t * B_, w_e);
        gemm(w_e, Wih_r, bih_r, bhh_r, gates, B_, 4 * H_, E_, 0);
        gemm(h_r, Whh_r, nullptr, nullptr, gates, B_, 4 * H_, H_, 1);
        lstm_pointwise<<<(B_ * H_ + 255) / 256, 256, 0, stream>>>(gates, c_r, h_r);
    }

    // r = h_r @ aff_r_W.T + aff_r_b   [B,F]
    gemm(h_r, aff_r_W, aff_r_b, nullptr, r_buf, B_, F_, H_, 0);

    // scores: ts = target @ r.T ; ds[d] = distractors[d] @ r.T
    gemm(target, r_buf, nullptr, nullptr, sc, B_, B_, F_, 0);
    for (int d = 0; d < D_; ++d)
        gemm(distract + (size_t)d * B_ * F_, r_buf, nullptr, nullptr,
             sc + (size_t)(1 + d) * B_ * B_, B_, B_, F_, 0);

    // loss + accuracy
    loss_rows<<<B_, 256, 0, stream>>>(sc, lp, lossp, accf);
    finalize_k<<<1, 256, 0, stream>>>(lossp, accf, (float*)d_out);
}

// Round 2
// 8189.397 us; speedup vs baseline: 3.0273x; 3.0273x over previous
//
#include <hip/hip_runtime.h>
#include <cmath>

// Problem constants (fixed by the reference file)
#define B_ 1024
#define F_ 4096
#define V_ 20000
#define E_ 512
#define H_ 1024
#define L_ 20
#define D_ 4

typedef __bf16 bf16x8 __attribute__((ext_vector_type(8)));
typedef float  f32x4  __attribute__((ext_vector_type(4)));

// ---------------------------------------------------------------------------
// Split-bf16 MFMA NT GEMM:
//   C[M,N] = A1[M,K1] @ W1[N,K1]^T (+ A2[M,K2] @ W2[N,K2]^T) (+ b1 + b2)
// fp32 inputs are split in-staging into bf16 hi/lo planes; per K-chunk we do
// 3 MFMAs (hi*hi + hi*lo + lo*hi), giving ~2^-16 relative error (fp32-class).
// Requirements: M % 128 == 0, K % 32 == 0 (all shapes here comply).
// N may be ragged (20000): W rows are guarded, C cols are guarded.
// Tile: 128x128, BK=32, 256 threads (4 waves, each 64x64 = 4x4 MFMA tiles).
// LDS 32 KB, unpadded [128][32] bf16 rows (64 B) -> fragment reads are a
// contiguous 1 KiB per wave quad-pattern = bank-conflict-free.
// ---------------------------------------------------------------------------
#define BM 128
#define BN 128
#define BK 32

__global__ __launch_bounds__(256, 2) void gemm_nt_split(
    const float* __restrict__ A1, const float* __restrict__ W1, int K1,
    const float* __restrict__ A2, const float* __restrict__ W2, int K2,
    const float* __restrict__ b1, const float* __restrict__ b2,
    float* __restrict__ C, int M, int N)
{
    __shared__ __align__(16) __bf16 As_hi[BM][BK];
    __shared__ __align__(16) __bf16 As_lo[BM][BK];
    __shared__ __align__(16) __bf16 Ws_hi[BN][BK];
    __shared__ __align__(16) __bf16 Ws_lo[BN][BK];

    const int tid  = threadIdx.x;
    const int bm   = blockIdx.y * BM;
    const int bn   = blockIdx.x * BN;
    // staging assignment: thread -> (row, 16-float half-row)
    const int srow = tid >> 1;          // 0..127
    const int scol = (tid & 1) * 16;    // 0 or 16
    // compute assignment
    const int lane = tid & 63;
    const int wv   = tid >> 6;          // wave 0..3
    const int wm   = (wv & 1) * 64;
    const int wn   = (wv >> 1) * 64;
    const int fm   = lane & 15;         // fragment m/n index
    const int fq   = lane >> 4;         // quad: k = fq*8 + j

    const bool wok = (bn + srow) < N;

    f32x4 acc[4][4];
#pragma unroll
    for (int i = 0; i < 4; ++i)
#pragma unroll
        for (int j = 0; j < 4; ++j) acc[i][j] = (f32x4){0.f, 0.f, 0.f, 0.f};

#pragma unroll 1
    for (int s = 0; s < 2; ++s) {
        const float* A = s ? A2 : A1;
        const float* W = s ? W2 : W1;
        const int    K = s ? K2 : K1;
        if (!A) continue;
        const float* Arow = A + (size_t)(bm + srow) * K;
        const float* Wrow = W + (size_t)(bn + srow) * K;

        for (int k0 = 0; k0 < K; k0 += BK) {
            // ---- global loads (issue before barrier; overlap prior compute)
            float av[16], wvv[16];
            const float* ap = Arow + k0 + scol;
            *(float4*)&av[0]   = *(const float4*)(ap + 0);
            *(float4*)&av[4]   = *(const float4*)(ap + 4);
            *(float4*)&av[8]   = *(const float4*)(ap + 8);
            *(float4*)&av[12]  = *(const float4*)(ap + 12);
            if (wok) {
                const float* wp = Wrow + k0 + scol;
                *(float4*)&wvv[0]  = *(const float4*)(wp + 0);
                *(float4*)&wvv[4]  = *(const float4*)(wp + 4);
                *(float4*)&wvv[8]  = *(const float4*)(wp + 8);
                *(float4*)&wvv[12] = *(const float4*)(wp + 12);
            } else {
#pragma unroll
                for (int v = 0; v < 16; ++v) wvv[v] = 0.f;
            }
            __syncthreads();   // prior readers done before we overwrite LDS

            // ---- split fp32 -> bf16 hi/lo, write LDS
#pragma unroll
            for (int u = 0; u < 16; u += 8) {
                bf16x8 hh, ll;
#pragma unroll
                for (int v = 0; v < 8; ++v) {
                    float x = av[u + v];
                    __bf16 h = (__bf16)x;
                    hh[v] = h;
                    ll[v] = (__bf16)(x - (float)h);
                }
                *(bf16x8*)&As_hi[srow][scol + u] = hh;
                *(bf16x8*)&As_lo[srow][scol + u] = ll;
            }
#pragma unroll
            for (int u = 0; u < 16; u += 8) {
                bf16x8 hh, ll;
#pragma unroll
                for (int v = 0; v < 8; ++v) {
                    float x = wvv[u + v];
                    __bf16 h = (__bf16)x;
                    hh[v] = h;
                    ll[v] = (__bf16)(x - (float)h);
                }
                *(bf16x8*)&Ws_hi[srow][scol + u] = hh;
                *(bf16x8*)&Ws_lo[srow][scol + u] = ll;
            }
            __syncthreads();

            // ---- MFMA over the K=32 chunk
            bf16x8 ah[4], al[4];
#pragma unroll
            for (int i = 0; i < 4; ++i) {
                ah[i] = *(const bf16x8*)&As_hi[wm + i * 16 + fm][fq * 8];
                al[i] = *(const bf16x8*)&As_lo[wm + i * 16 + fm][fq * 8];
            }
#pragma unroll
            for (int j = 0; j < 4; ++j) {
                bf16x8 bh = *(const bf16x8*)&Ws_hi[wn + j * 16 + fm][fq * 8];
                bf16x8 bl = *(const bf16x8*)&Ws_lo[wn + j * 16 + fm][fq * 8];
#pragma unroll
                for (int i = 0; i < 4; ++i) {
                    acc[i][j] = __builtin_amdgcn_mfma_f32_16x16x32_bf16(
                        al[i], bh, acc[i][j], 0, 0, 0);
                    acc[i][j] = __builtin_amdgcn_mfma_f32_16x16x32_bf16(
                        ah[i], bl, acc[i][j], 0, 0, 0);
                    acc[i][j] = __builtin_amdgcn_mfma_f32_16x16x32_bf16(
                        ah[i], bh, acc[i][j], 0, 0, 0);
                }
            }
        }
    }

    // ---- epilogue: C/D layout col = lane&15, row = quad*4 + reg
#pragma unroll
    for (int j = 0; j < 4; ++j) {
        int col = bn + wn + j * 16 + fm;
        if (col >= N) continue;
        float badd = (b1 ? b1[col] : 0.f) + (b2 ? b2[col] : 0.f);
#pragma unroll
        for (int i = 0; i < 4; ++i) {
            int row0 = bm + wm + i * 16 + fq * 4;
            f32x4 v = acc[i][j];
#pragma unroll
            for (int r = 0; r < 4; ++r)
                C[(size_t)(row0 + r) * N + col] = v[r] + badd;
        }
    }
}

// ---------------------------------------------------------------------------
// LSTM pointwise: gates [B,4H] (i,f,g,o), updates c,h in place.
// ---------------------------------------------------------------------------
__global__ __launch_bounds__(256) void lstm_pointwise(
    const float* __restrict__ gates, float* __restrict__ c, float* __restrict__ h)
{
    int i = blockIdx.x * blockDim.x + threadIdx.x;
    if (i >= B_ * H_) return;
    int b = i / H_, k = i % H_;
    const float* g = gates + (size_t)b * 4 * H_;
    float gi = g[k], gf = g[H_ + k], gg = g[2 * H_ + k], go = g[3 * H_ + k];
    float si = 1.f / (1.f + expf(-gi));
    float sf = 1.f / (1.f + expf(-gf));
    float so = 1.f / (1.f + expf(-go));
    float cn = sf * c[i] + si * tanhf(gg);
    c[i] = cn;
    h[i] = so * tanhf(cn);
}

// ---------------------------------------------------------------------------
// Per-row argmax (first-occurrence, numpy semantics) + online logsumexp.
// ---------------------------------------------------------------------------
__global__ __launch_bounds__(256) void row_argmax_lse(
    const float* __restrict__ logits, int* __restrict__ tok,
    float* __restrict__ lp, int need_lp)
{
    int b = blockIdx.x;
    const float* row = logits + (size_t)b * V_;
    int tid = threadIdx.x;
    float m = -INFINITY; int mi = 0;
    float lm = -INFINITY, ls = 0.f;
    for (int j = tid; j < V_; j += 256) {
        float v = row[j];
        if (v > m) { m = v; mi = j; }
        if (need_lp) {
            if (v > lm) { ls = ls * expf(lm - v) + 1.f; lm = v; }
            else ls += expf(v - lm);
        }
    }
    __shared__ float sm[256]; __shared__ int si[256];
    __shared__ float slm[256], sls[256];
    sm[tid] = m; si[tid] = mi; slm[tid] = lm; sls[tid] = ls;
    __syncthreads();
    for (int s = 128; s > 0; s >>= 1) {
        if (tid < s) {
            float vm = sm[tid + s]; int vi = si[tid + s];
            if (vm > sm[tid] || (vm == sm[tid] && vi < si[tid])) {
                sm[tid] = vm; si[tid] = vi;
            }
            if (need_lp) {
                float am = slm[tid], as = sls[tid];
                float bm2 = slm[tid + s], bs = sls[tid + s];
                if (am >= bm2) {
                    sls[tid] = as + bs * expf(bm2 - am);
                } else {
                    sls[tid] = bs + as * expf(am - bm2);
                    slm[tid] = bm2;
                }
            }
        }
        __syncthreads();
    }
    if (tid == 0) {
        tok[b] = si[0];
        if (need_lp) lp[b] = sm[0] - (slm[0] + logf(sls[0]));
    }
}

// ---------------------------------------------------------------------------
// Embedding gathers
// ---------------------------------------------------------------------------
__global__ __launch_bounds__(128) void gather_emb(
    const float* __restrict__ emb, const int* __restrict__ tok,
    float* __restrict__ out)
{
    int b = blockIdx.x;
    int t = tok[b];
    const float4* src = (const float4*)(emb + (size_t)t * E_);
    float4* dst = (float4*)(out + (size_t)b * E_);
    for (int e = threadIdx.x; e < E_ / 4; e += blockDim.x) dst[e] = src[e];
}

__global__ __launch_bounds__(128) void broadcast_emb(
    const float* __restrict__ emb, const int* __restrict__ sidx,
    float* __restrict__ out)
{
    int b = blockIdx.x;
    int t = sidx[0];
    const float4* src = (const float4*)(emb + (size_t)t * E_);
    float4* dst = (float4*)(out + (size_t)b * E_);
    for (int e = threadIdx.x; e < E_ / 4; e += blockDim.x) dst[e] = src[e];
}

__global__ __launch_bounds__(256) void zero_f32(float* __restrict__ p, int n)
{
    int i = blockIdx.x * blockDim.x + threadIdx.x;
    if (i < n) p[i] = 0.f;
}

// ---------------------------------------------------------------------------
// Loss rows: sc = [5, B, B] (ts then 4 distractor score mats), lp [B].
// ---------------------------------------------------------------------------
__global__ __launch_bounds__(256) void loss_rows(
    const float* __restrict__ sc, const float* __restrict__ lp,
    float* __restrict__ loss_part, float* __restrict__ acc_flag)
{
    int i = blockIdx.x; int tid = threadIdx.x;
    const float* tsrow = sc + (size_t)i * B_;
    float lsum = 0.f, tps = 0.f;
    float dps[4] = {0.f, 0.f, 0.f, 0.f};
    for (int j = tid; j < B_; j += 256) {
        float tsv = tsrow[j];
        float hv = 0.f;
#pragma unroll
        for (int d = 0; d < 4; ++d) {
            float dv = sc[((size_t)(1 + d) * B_ + i) * B_ + j];
            float t = 1.f - tsv + dv;
            hv += (t > 0.f) ? t : 0.f;
            dps[d] += expf(dv);
        }
        lsum += hv * lp[j];
        tps += expf(tsv);
    }
    __shared__ float red[6][256];
    red[0][tid] = lsum; red[1][tid] = tps;
    red[2][tid] = dps[0]; red[3][tid] = dps[1];
    red[4][tid] = dps[2]; red[5][tid] = dps[3];
    __syncthreads();
    for (int s = 128; s > 0; s >>= 1) {
        if (tid < s) {
#pragma unroll
            for (int q = 0; q < 6; ++q) red[q][tid] += red[q][tid + s];
        }
        __syncthreads();
    }
    if (tid == 0) {
        loss_part[i] = -red[0][0];
        float tp = red[1][0];
        float mx = fmaxf(fmaxf(red[2][0], red[3][0]), fmaxf(red[4][0], red[5][0]));
        acc_flag[i] = (tp >= mx) ? 1.f : 0.f;
    }
}

__global__ __launch_bounds__(256) void finalize_k(
    const float* __restrict__ loss_part, const float* __restrict__ acc_flag,
    float* __restrict__ out)
{
    int tid = threadIdx.x;
    float ls = 0.f, ac = 0.f;
    for (int i = tid; i < B_; i += 256) { ls += loss_part[i]; ac += acc_flag[i]; }
    __shared__ float s1[256], s2[256];
    s1[tid] = ls; s2[tid] = ac;
    __syncthreads();
    for (int s = 128; s > 0; s >>= 1) {
        if (tid < s) { s1[tid] += s1[tid + s]; s2[tid] += s2[tid + s]; }
        __syncthreads();
    }
    if (tid == 0) {
        out[0] = s1[0] / ((float)B_ * (float)B_);
        out[1] = s2[0] / (float)B_;
    }
}

// ---------------------------------------------------------------------------
// Host launcher
// ---------------------------------------------------------------------------
extern "C" void kernel_launch(void* const* d_in, const int* in_sizes, int n_in,
                              void* d_out, int out_size, void* d_ws, size_t ws_size,
                              hipStream_t stream)
{
    const float* target    = (const float*)d_in[0];
    const float* distract  = (const float*)d_in[1];
    const int*   start_tok = (const int*)d_in[2];
    const float* emb_s   = (const float*)d_in[4];
    const float* Wih_s   = (const float*)d_in[5];
    const float* Whh_s   = (const float*)d_in[6];
    const float* bih_s   = (const float*)d_in[7];
    const float* bhh_s   = (const float*)d_in[8];
    const float* aff_s_W = (const float*)d_in[9];
    const float* aff_s_b = (const float*)d_in[10];
    const float* probs_W = (const float*)d_in[11];
    const float* probs_b = (const float*)d_in[12];
    const float* emb_r   = (const float*)d_in[13];
    const float* Wih_r   = (const float*)d_in[14];
    const float* Whh_r   = (const float*)d_in[15];
    const float* bih_r   = (const float*)d_in[16];
    const float* bhh_r   = (const float*)d_in[17];
    const float* aff_r_W = (const float*)d_in[18];
    const float* aff_r_b = (const float*)d_in[19];

    float* ws = (float*)d_ws;
    // workspace layout (float offsets) — identical footprint to the proven
    // baseline layout (max ~119.7 MB).
    const size_t OFF_HS     = 0;                 // [B,H]
    const size_t OFF_CS     = 1048576;           // [B,H]
    const size_t OFF_WE     = 2097152;           // [B,E]
    const size_t OFF_GATES  = 2621440;           // [B,4H]
    const size_t OFF_HR     = 6815744;           // [B,H]
    const size_t OFF_CR     = 7864320;           // [B,H]
    const size_t OFF_LP     = 8912896;           // [B]
    const size_t OFF_LOSSP  = 8916992;           // [B]
    const size_t OFF_ACCF   = 8921088;           // [B]
    const size_t OFF_MSG    = 8925184;           // int [L,B]
    const size_t OFF_LOGITS = 9437184;           // [B,V]
    const size_t OFF_R      = 9437184;           // [B,F]   reuses logits region
    const size_t OFF_SC     = 13631488;          // [5,B,B] after r region

    float* h_s    = ws + OFF_HS;
    float* c_s    = ws + OFF_CS;
    float* w_e    = ws + OFF_WE;
    float* gates  = ws + OFF_GATES;
    float* h_r    = ws + OFF_HR;
    float* c_r    = ws + OFF_CR;
    float* lp     = ws + OFF_LP;
    float* lossp  = ws + OFF_LOSSP;
    float* accf   = ws + OFF_ACCF;
    int*   msg    = (int*)(ws + OFF_MSG);
    float* logits = ws + OFF_LOGITS;
    float* r_buf  = ws + OFF_R;
    float* sc     = ws + OFF_SC;

    auto gemm = [&](const float* A1, const float* W1, int K1,
                    const float* A2, const float* W2, int K2,
                    const float* b1, const float* b2,
                    float* C, int M, int N) {
        dim3 grid((N + BN - 1) / BN, M / BM);
        gemm_nt_split<<<grid, dim3(256), 0, stream>>>(A1, W1, K1, A2, W2, K2,
                                                      b1, b2, C, M, N);
    };

    // ---- Sender ----
    gemm(target, aff_s_W, F_, nullptr, nullptr, 0, aff_s_b, nullptr, h_s, B_, H_);
    zero_f32<<<(B_ * H_ + 255) / 256, 256, 0, stream>>>(c_s, B_ * H_);
    broadcast_emb<<<B_, 128, 0, stream>>>(emb_s, start_tok, w_e);

    for (int t = 0; t < L_; ++t) {
        gemm(w_e, Wih_s, E_, h_s, Whh_s, H_, bih_s, bhh_s, gates, B_, 4 * H_);
        lstm_pointwise<<<(B_ * H_ + 255) / 256, 256, 0, stream>>>(gates, c_s, h_s);
        gemm(h_s, probs_W, H_, nullptr, nullptr, 0, probs_b, nullptr, logits, B_, V_);
        row_argmax_lse<<<B_, 256, 0, stream>>>(logits, msg + (size_t)t * B_, lp,
                                               (t == L_ - 1) ? 1 : 0);
        if (t < L_ - 1)
            gather_emb<<<B_, 128, 0, stream>>>(emb_s, msg + (size_t)t * B_, w_e);
    }

    // ---- Receiver ----
    zero_f32<<<(B_ * H_ + 255) / 256, 256, 0, stream>>>(h_r, B_ * H_);
    zero_f32<<<(B_ * H_ + 255) / 256, 256, 0, stream>>>(c_r, B_ * H_);
    for (int t = 0; t < L_; ++t) {
        gather_emb<<<B_, 128, 0, stream>>>(emb_r, msg + (size_t)t * B_, w_e);
        gemm(w_e, Wih_r, E_, h_r, Whh_r, H_, bih_r, bhh_r, gates, B_, 4 * H_);
        lstm_pointwise<<<(B_ * H_ + 255) / 256, 256, 0, stream>>>(gates, c_r, h_r);
    }

    // r = h_r @ aff_r_W.T + aff_r_b   [B,F]
    gemm(h_r, aff_r_W, H_, nullptr, nullptr, 0, aff_r_b, nullptr, r_buf, B_, F_);

    // scores: ts = target @ r.T ; ds = distractors(flattened [4B,F]) @ r.T
    gemm(target, r_buf, F_, nullptr, nullptr, 0, nullptr, nullptr, sc, B_, B_);
    gemm(distract, r_buf, F_, nullptr, nullptr, 0, nullptr, nullptr,
         sc + (size_t)B_ * B_, D_ * B_, B_);

    // loss + accuracy
    loss_rows<<<B_, 256, 0, stream>>>(sc, lp, lossp, accf);
    finalize_k<<<1, 256, 0, stream>>>(lossp, accf, (float*)d_out);
}